// Round 1
// baseline (268.595 us; speedup 1.0000x reference)
//
#include <hip/hip_runtime.h>

// Problem: B=4, N=8, C=256, H=64, W=64, D=512 (single query per batch).
// Algebraic collapse:
//   gqk[b,c]  = g[c] * D^-0.5 * sum_d Wkv[d,c] * qp[b,d],  qp = Wq @ q[b]
//   dots[n]   = inv_rms[n] * sum_c cp[n,c] * gqk[b,c]
//   out[i]    = sum_c Wovg[i,c] * t[c] + bo[i],
//   Wovg[i,c] = g[c] * sum_d Wo[i,d] * Wkv[D+d,c]
//   t[c]      = sum_n att[n] * inv_rms[n] * cp[n,c]
// => c is read exactly once from HBM; final projection is a small GEMM done in
//    bf16 MFMA (threshold is bf16-level: 6.9e-2).

typedef __attribute__((ext_vector_type(8))) short short8;
typedef __attribute__((ext_vector_type(4))) float floatx4;

static __device__ __forceinline__ short f2bf(float f) {
  unsigned u = __float_as_uint(f);
  u += 0x7fffu + ((u >> 16) & 1u);   // round-to-nearest-even
  return (short)(u >> 16);
}

// ws layout: [0,131072) bytes: WovgB bf16 [256][256]; [131072,135168): gqk f32 [4][256]
__global__ __launch_bounds__(256) void pre_kernel(
    const float* __restrict__ q, const float* __restrict__ g,
    const float* __restrict__ Wq, const float* __restrict__ Wkv,
    const float* __restrict__ Wo, unsigned char* __restrict__ ws) {
  short* WovgB = (short*)ws;
  float* gqk = (float*)(ws + 131072);
  const int blk = blockIdx.x, tid = threadIdx.x;
  if (blk < 256) {
    // Wovg[i][c] = g[c] * sum_d Wo[i*512+d] * Wkv[(512+d)*256 + c]
    const int i = blk, c = tid;
    float s = 0.f;
    #pragma unroll 8
    for (int d = 0; d < 512; ++d)
      s = fmaf(Wo[i * 512 + d], Wkv[(512 + d) * 256 + c], s);
    WovgB[i * 256 + c] = f2bf(s * g[c]);
  } else {
    const int b = blk - 256;
    __shared__ float qps[512];
    for (int d = tid; d < 512; d += 256) {
      float s = 0.f;
      #pragma unroll 8
      for (int cc = 0; cc < 256; ++cc)
        s = fmaf(Wq[d * 256 + cc], q[b * 256 + cc], s);
      qps[d] = s;
    }
    __syncthreads();
    const int c = tid;
    float s = 0.f;
    #pragma unroll 8
    for (int d = 0; d < 512; ++d)
      s = fmaf(Wkv[d * 256 + c], qps[d], s);
    gqk[b * 256 + c] = s * g[c] * 0.044194173824159216f;  // 512^-0.5
  }
}

// One block = one row (b,h): 64 pixels. 512 threads: wave cg (=tid>>6) owns
// channels [cg*32, cg*32+32), lane = w. Single pass over c with online softmax;
// then 256x64x256 projection via bf16 MFMA 16x16x32.
__global__ __launch_bounds__(512) void attn_kernel(
    const float* __restrict__ cin, const float* __restrict__ bo,
    const unsigned char* __restrict__ ws, float* __restrict__ out) {
  const short* WovgB = (const short*)ws;
  const float* gqk = (const float*)(ws + 131072);
  const int blk = blockIdx.x;        // 256 blocks
  const int b = blk >> 6, h = blk & 63;
  const int tid = threadIdx.x;
  const int lane = tid & 63;         // w (phase 1) / MFMA lane (phase 3)
  const int cg = tid >> 6;           // 0..7

  __shared__ short tB[8][4][64][8];  // 32 KB: t in B-fragment-linear order (bf16)
  __shared__ float red_ssq[8][64];
  __shared__ float red_dot[8][64];
  __shared__ float m_s[64], z_s[64], al_s[64], wn_s[64];

  // per-thread gqk slice (channels are fixed across tokens)
  float rg[32];
  #pragma unroll
  for (int j = 0; j < 32; ++j) rg[j] = gqk[b * 256 + cg * 32 + j];

  if (tid < 64) { m_s[tid] = -1e30f; z_s[tid] = 0.f; }
  float t_reg[32];
  #pragma unroll
  for (int j = 0; j < 32; ++j) t_reg[j] = 0.f;
  __syncthreads();

  const float* cb = cin + ((size_t)(b * 8) * 256 + cg * 32) * 4096 + h * 64 + lane;
  for (int n = 0; n < 8; ++n) {
    const float* cp = cb + (size_t)n * 256 * 4096;
    float vals[32];
    #pragma unroll
    for (int j = 0; j < 32; ++j) vals[j] = cp[(size_t)j * 4096];  // 256B/wave, coalesced
    float ssq = 0.f, dt = 0.f;
    #pragma unroll
    for (int j = 0; j < 32; ++j) {
      ssq = fmaf(vals[j], vals[j], ssq);
      dt = fmaf(vals[j], rg[j], dt);
    }
    red_ssq[cg][lane] = ssq;
    red_dot[cg][lane] = dt;
    __syncthreads();
    if (tid < 64) {  // per-pixel scalars: RMS + online softmax update
      float S = 0.f, Dt = 0.f;
      #pragma unroll
      for (int gg = 0; gg < 8; ++gg) { S += red_ssq[gg][tid]; Dt += red_dot[gg][tid]; }
      const float invr = rsqrtf(S * (1.f / 256.f) + 1e-6f);
      const float d = Dt * invr;
      const float mo = m_s[tid];
      const float mn = fmaxf(mo, d);
      const float al = __expf(mo - mn);  // 0 on first token (mo=-1e30)
      const float e = __expf(d - mn);
      z_s[tid] = z_s[tid] * al + e;
      m_s[tid] = mn;
      al_s[tid] = al;
      wn_s[tid] = e * invr;
    }
    __syncthreads();
    const float al = al_s[lane], wn = wn_s[lane];
    #pragma unroll
    for (int j = 0; j < 32; ++j) t_reg[j] = fmaf(wn, vals[j], t_reg[j] * al);
  }

  // write normalized t as bf16 into fragment order:
  // reader lane L=(q*16+m) of tile (s,nt) wants ch=s*32+q*8+j, px=nt*16+m.
  {
    const float invZ = 1.f / z_s[lane];
    const int nt = lane >> 4, m = lane & 15;
    #pragma unroll
    for (int qq = 0; qq < 4; ++qq) {
      short8 pk;
      #pragma unroll
      for (int jj = 0; jj < 8; ++jj) pk[jj] = f2bf(t_reg[qq * 8 + jj] * invZ);
      *(short8*)(&tB[cg][nt][qq * 16 + m][0]) = pk;
    }
  }
  __syncthreads();

  // phase 3: out[256 i][64 px] = Wovg(bf16) @ t(bf16); wave ig -> 32 i-rows
  const int ig = __builtin_amdgcn_readfirstlane(tid >> 6);
  const int q = lane >> 4, m = lane & 15;
  const short8* Av = (const short8*)WovgB;  // A frag at [i*32 + s*4 + q]
  const short8* Bv = (const short8*)tB;     // B frag at [(s*4+nt)*64 + lane]
  floatx4 acc[2][4];
  #pragma unroll
  for (int mt = 0; mt < 2; ++mt)
    #pragma unroll
    for (int nt = 0; nt < 4; ++nt) acc[mt][nt] = (floatx4){0.f, 0.f, 0.f, 0.f};
  #pragma unroll
  for (int s = 0; s < 8; ++s) {
    const short8 a0 = Av[(ig * 32 + m) * 32 + s * 4 + q];
    const short8 a1 = Av[(ig * 32 + 16 + m) * 32 + s * 4 + q];
    #pragma unroll
    for (int nt = 0; nt < 4; ++nt) {
      const short8 bf = Bv[(s * 4 + nt) * 64 + lane];
      acc[0][nt] = __builtin_amdgcn_mfma_f32_16x16x32_bf16(a0, bf, acc[0][nt], 0, 0, 0);
      acc[1][nt] = __builtin_amdgcn_mfma_f32_16x16x32_bf16(a1, bf, acc[1][nt], 0, 0, 0);
    }
  }
  // epilogue: D layout col=lane&15(px), row=q*4+r(i)
  float bov[2][4];
  #pragma unroll
  for (int mt = 0; mt < 2; ++mt)
    #pragma unroll
    for (int r = 0; r < 4; ++r) bov[mt][r] = bo[ig * 32 + mt * 16 + q * 4 + r];
  float* ob = out + ((size_t)b * 256) * 4096 + h * 64;
  #pragma unroll
  for (int mt = 0; mt < 2; ++mt)
    #pragma unroll
    for (int nt = 0; nt < 4; ++nt)
      #pragma unroll
      for (int r = 0; r < 4; ++r) {
        const int i = ig * 32 + mt * 16 + q * 4 + r;
        const int px = nt * 16 + m;
        ob[(size_t)i * 4096 + px] = acc[mt][nt][r] + bov[mt][r];
      }
}

extern "C" void kernel_launch(void* const* d_in, const int* in_sizes, int n_in,
                              void* d_out, int out_size, void* d_ws, size_t ws_size,
                              hipStream_t stream) {
  const float* q   = (const float*)d_in[0];
  const float* c   = (const float*)d_in[1];
  const float* g   = (const float*)d_in[2];
  const float* Wq  = (const float*)d_in[3];
  const float* Wkv = (const float*)d_in[4];
  const float* Wo  = (const float*)d_in[5];
  const float* bo  = (const float*)d_in[6];
  float* out = (float*)d_out;
  unsigned char* ws = (unsigned char*)d_ws;  // needs 135168 bytes
  pre_kernel<<<260, 256, 0, stream>>>(q, g, Wq, Wkv, Wo, ws);
  attn_kernel<<<256, 512, 0, stream>>>(c, bo, ws, out);
}

// Round 2
// 249.441 us; speedup vs baseline: 1.0768x; 1.0768x over previous
//
#include <hip/hip_runtime.h>

// B=4, N=8, C=256, H=64, W=64, D=512 (single query per batch).
// Algebraic collapse (see R1): c is read exactly once; K and V never formed.
//   gqk[b,c]  = g[c] * D^-0.5 * (Wkv_upper^T (Wq q_b))[c]
//   dots[n]   = inv_rms[n] * <cp[n,:], gqk[b,:]>   (per pixel)
//   t[c]      = sum_n softmax_n * inv_rms[n] * cp[n,c]
//   out       = Wovg @ t + bo,  Wovg = Wo @ Wkv_lower * diag(g)  (bf16 MFMA)
//
// R2: 512 blocks (half-row each) -> 2 blocks/CU; 1 barrier/token via
// shfl_xor(32) + double-buffered LDS partials + per-lane redundant softmax;
// Wovg stored in A-fragment-linear order for coalesced phase-3 loads.

typedef __attribute__((ext_vector_type(8))) short short8;
typedef __attribute__((ext_vector_type(4))) float floatx4;

static __device__ __forceinline__ short f2bf(float f) {
  unsigned u = __float_as_uint(f);
  u += 0x7fffu + ((u >> 16) & 1u);   // round-to-nearest-even
  return (short)(u >> 16);
}

// ws: [0,131072) WovgB bf16, A-fragment-linear: element (i,c) at short index
//     ((((i>>4)*8 + (c>>5))*4 + ((c>>3)&3))*16 + (i&15))*8 + (c&7)
//     [131072,135168) gqk f32 [4][256]
__global__ __launch_bounds__(256) void pre_kernel(
    const float* __restrict__ q, const float* __restrict__ g,
    const float* __restrict__ Wq, const float* __restrict__ Wkv,
    const float* __restrict__ Wo, unsigned char* __restrict__ ws) {
  short* WovgB = (short*)ws;
  float* gqk = (float*)(ws + 131072);
  const int blk = blockIdx.x, tid = threadIdx.x;
  if (blk < 256) {
    const int i = blk, c = tid;
    float s = 0.f;
    #pragma unroll 16
    for (int d = 0; d < 512; ++d)
      s = fmaf(Wo[i * 512 + d], Wkv[(512 + d) * 256 + c], s);
    const int it = i >> 4, m = i & 15;
    const int sg = c >> 5, q2 = (c >> 3) & 3, jj = c & 7;
    WovgB[((((it * 8 + sg) * 4 + q2) * 16) + m) * 8 + jj] = f2bf(s * g[c]);
  } else {
    const int b = blk - 256;
    __shared__ float qps[512];
    for (int d = tid; d < 512; d += 256) {
      float s = 0.f;
      #pragma unroll 16
      for (int cc = 0; cc < 256; ++cc)
        s = fmaf(Wq[d * 256 + cc], q[b * 256 + cc], s);
      qps[d] = s;
    }
    __syncthreads();
    const int c = tid;
    float s = 0.f;
    #pragma unroll 16
    for (int d = 0; d < 512; ++d)
      s = fmaf(Wkv[d * 256 + c], qps[d], s);
    gqk[b * 256 + c] = s * g[c] * 0.044194173824159216f;  // 512^-0.5
  }
}

// Block = (b, h, half-row): 32 px, 256 threads = 4 waves. Lane = cgh*32+px;
// channel group cg = wave*2+cgh owns ch [cg*32, cg*32+32).
__global__ __launch_bounds__(256, 2) void attn_kernel(
    const float* __restrict__ cin, const float* __restrict__ bo,
    const unsigned char* __restrict__ ws, float* __restrict__ out) {
  const short8* Av = (const short8*)ws;
  const float* gqk = (const float*)(ws + 131072);
  const int blk = blockIdx.x;                 // 512 blocks
  const int b = blk >> 7, h = (blk >> 1) & 63, hf = blk & 1;
  const int tid = threadIdx.x;
  const int lane = tid & 63, w = tid >> 6;
  const int px = lane & 31, cgh = lane >> 5;
  const int cg = w * 2 + cgh;

  __shared__ short tB[8][2][64][8];           // 16 KB, B-fragment-linear
  __shared__ float redS[2][4][32], redD[2][4][32];

  float rg[32];
  #pragma unroll
  for (int j = 0; j < 32; ++j) rg[j] = gqk[b * 256 + cg * 32 + j];

  float t_reg[32];
  #pragma unroll
  for (int j = 0; j < 32; ++j) t_reg[j] = 0.f;
  float mM = -1e30f, zZ = 0.f;

  const float* cb = cin + ((size_t)(b * 8) * 256 + cg * 32) * 4096
                        + h * 64 + hf * 32 + px;
  for (int n = 0; n < 8; ++n) {
    const float* cp = cb + (size_t)n * 256 * 4096;
    float vals[32];
    #pragma unroll
    for (int j = 0; j < 32; ++j) vals[j] = cp[(size_t)j * 4096];
    float ssq = 0.f, dt = 0.f;
    #pragma unroll
    for (int j = 0; j < 32; ++j) {
      ssq = fmaf(vals[j], vals[j], ssq);
      dt = fmaf(vals[j], rg[j], dt);
    }
    ssq += __shfl_xor(ssq, 32);               // combine the wave's 2 cg halves
    dt  += __shfl_xor(dt, 32);
    if (cgh == 0) { redS[n & 1][w][px] = ssq; redD[n & 1][w][px] = dt; }
    __syncthreads();                          // the only barrier per token
    float S = 0.f, Dt = 0.f;
    #pragma unroll
    for (int ww = 0; ww < 4; ++ww) { S += redS[n & 1][ww][px]; Dt += redD[n & 1][ww][px]; }
    const float invr = rsqrtf(S * (1.f / 256.f) + 1e-6f);
    const float d = Dt * invr;
    const float mn = fmaxf(mM, d);
    const float al = __expf(mM - mn);         // 0 on first token
    const float e = __expf(d - mn);
    zZ = zZ * al + e;
    mM = mn;
    const float wn = e * invr;
    #pragma unroll
    for (int j = 0; j < 32; ++j) t_reg[j] = fmaf(wn, vals[j], t_reg[j] * al);
  }

  // write normalized t (bf16) in B-fragment order:
  // reader lane L=(q*16+m) of (s,nt) wants ch=s*32+q*8+j, px=nt*16+m
  {
    const float invZ = 1.f / zZ;
    const int nt = px >> 4, mm = px & 15;
    #pragma unroll
    for (int qq = 0; qq < 4; ++qq) {
      short8 pk;
      #pragma unroll
      for (int jj = 0; jj < 8; ++jj) pk[jj] = f2bf(t_reg[qq * 8 + jj] * invZ);
      *(short8*)(&tB[cg][nt][qq * 16 + mm][0]) = pk;
    }
  }
  __syncthreads();

  // phase 3: out[256 i][32 px] = Wovg(bf16) @ t(bf16); wave ig -> 64 i-rows
  const int ig = __builtin_amdgcn_readfirstlane(w);
  const int q = lane >> 4, m = lane & 15;
  const short8* Bv = (const short8*)tB;
  floatx4 acc[4][2];
  #pragma unroll
  for (int mt = 0; mt < 4; ++mt)
    #pragma unroll
    for (int nt = 0; nt < 2; ++nt) acc[mt][nt] = (floatx4){0.f, 0.f, 0.f, 0.f};
  #pragma unroll
  for (int s = 0; s < 8; ++s) {
    short8 a[4];
    #pragma unroll
    for (int mt = 0; mt < 4; ++mt)            // coalesced: 16 B/lane, 1 KB/wave
      a[mt] = Av[(((ig * 4 + mt) * 8 + s) * 4 + q) * 16 + m];
    #pragma unroll
    for (int nt = 0; nt < 2; ++nt) {
      const short8 bf = Bv[(s * 2 + nt) * 64 + lane];
      #pragma unroll
      for (int mt = 0; mt < 4; ++mt)
        acc[mt][nt] = __builtin_amdgcn_mfma_f32_16x16x32_bf16(a[mt], bf, acc[mt][nt], 0, 0, 0);
    }
  }
  // epilogue: D layout col=lane&15(px), row=q*4+r(i)
  float* ob = out + (size_t)b * 256 * 4096 + h * 64 + hf * 32;
  #pragma unroll
  for (int mt = 0; mt < 4; ++mt) {
    float bov[4];
    #pragma unroll
    for (int r = 0; r < 4; ++r) bov[r] = bo[ig * 64 + mt * 16 + q * 4 + r];
    #pragma unroll
    for (int nt = 0; nt < 2; ++nt)
      #pragma unroll
      for (int r = 0; r < 4; ++r) {
        const int i = ig * 64 + mt * 16 + q * 4 + r;
        ob[(size_t)i * 4096 + nt * 16 + m] = acc[mt][nt][r] + bov[r];
      }
  }
}

extern "C" void kernel_launch(void* const* d_in, const int* in_sizes, int n_in,
                              void* d_out, int out_size, void* d_ws, size_t ws_size,
                              hipStream_t stream) {
  const float* q   = (const float*)d_in[0];
  const float* c   = (const float*)d_in[1];
  const float* g   = (const float*)d_in[2];
  const float* Wq  = (const float*)d_in[3];
  const float* Wkv = (const float*)d_in[4];
  const float* Wo  = (const float*)d_in[5];
  const float* bo  = (const float*)d_in[6];
  float* out = (float*)d_out;
  unsigned char* ws = (unsigned char*)d_ws;   // needs 135168 bytes
  pre_kernel<<<260, 256, 0, stream>>>(q, g, Wq, Wkv, Wo, ws);
  attn_kernel<<<512, 256, 0, stream>>>(c, bo, ws, out);
}